// Round 1
// baseline (270.499 us; speedup 1.0000x reference)
//
#include <hip/hip_runtime.h>
#include <stdint.h>

#define Mdim 4096
#define Kdim 4096
#define Ndim 4096

typedef __attribute__((ext_vector_type(4))) int v4i;
typedef __attribute__((ext_vector_type(16))) int v16i;

// Async global->LDS, 16B per lane. LDS dest is wave-uniform base + lane*16,
// so lds ptr must be lane-contiguous (t*16). Global address may be per-lane.
__device__ __forceinline__ void gload_lds16(const void* g, void* l) {
  __builtin_amdgcn_global_load_lds(
      (__attribute__((address_space(1))) void*)(uintptr_t)g,
      (__attribute__((address_space(3))) void*)(uint32_t)(uintptr_t)l,
      16, 0, 0);
}

// ---- pack x (int32 [M][K] -> int8 [M][K]) + row sums -----------------------
__global__ __launch_bounds__(256) void pack_x_kernel(const int* __restrict__ x,
                                                     char* __restrict__ x8,
                                                     int* __restrict__ rsx) {
  const int row = blockIdx.x;
  const int t = threadIdx.x;
  const int4* src = (const int4*)(x + (size_t)row * Kdim) + t * 4;
  int sum = 0;
  int p[4];
#pragma unroll
  for (int i = 0; i < 4; ++i) {
    int4 v = src[i];
    sum += v.x + v.y + v.z + v.w;
    p[i] = (v.x & 0xff) | ((v.y & 0xff) << 8) | ((v.z & 0xff) << 16) | (v.w << 24);
  }
  ((int4*)x8)[(size_t)row * 256 + t] = make_int4(p[0], p[1], p[2], p[3]);
#pragma unroll
  for (int o = 32; o > 0; o >>= 1) sum += __shfl_down(sum, o, 64);
  __shared__ int red[4];
  if ((t & 63) == 0) red[t >> 6] = sum;
  __syncthreads();
  if (t == 0) rsx[row] = red[0] + red[1] + red[2] + red[3];
}

// ---- pack + transpose y (int32 [K][N] -> int8 (y-128) [N][K]) --------------
__global__ __launch_bounds__(256) void pack_yt_kernel(const int* __restrict__ y,
                                                      char* __restrict__ yt) {
  __shared__ char tile[64][68];  // pad 68: odd word stride -> conflict-light
  const int t = threadIdx.x;
  const int n0 = blockIdx.x * 64;
  const int k0 = blockIdx.y * 64;
  const int c = t & 63;
  const int r4 = t >> 6;
#pragma unroll
  for (int it = 0; it < 16; ++it) {
    const int r = it * 4 + r4;
    const int v = y[(size_t)(k0 + r) * Ndim + n0 + c];
    tile[c][r] = (char)(v - 128);
  }
  __syncthreads();
  const int orow = t >> 4;        // 0..15
  const int ocb = (t & 15) * 4;   // k offset, 4B per thread
#pragma unroll
  for (int it = 0; it < 4; ++it) {
    const int rr = it * 16 + orow;
    int wv = (tile[rr][ocb] & 0xff) | ((tile[rr][ocb + 1] & 0xff) << 8) |
             ((tile[rr][ocb + 2] & 0xff) << 16) | (tile[rr][ocb + 3] << 24);
    *(int*)(yt + (size_t)(n0 + rr) * Kdim + k0 + ocb) = wv;
  }
}

// ---- column sums of y8 (= sum over k of yt[n][k]) --------------------------
__global__ __launch_bounds__(256) void colsum_kernel(const char* __restrict__ yt,
                                                     int* __restrict__ csy) {
  const int n = blockIdx.x;
  const int t = threadIdx.x;
  int4 v = ((const int4*)yt)[(size_t)n * 256 + t];
  int words[4] = {v.x, v.y, v.z, v.w};
  int s = 0;
#pragma unroll
  for (int i = 0; i < 4; ++i) {
    int w = words[i];
    s += (int)(char)(w) + (int)(char)(w >> 8) + (int)(char)(w >> 16) + (w >> 24);
  }
#pragma unroll
  for (int o = 32; o > 0; o >>= 1) s += __shfl_down(s, o, 64);
  __shared__ int red[4];
  if ((t & 63) == 0) red[t >> 6] = s;
  __syncthreads();
  if (t == 0) csy[n] = red[0] + red[1] + red[2] + red[3];
}

// ---- i8 GEMM: C_f32 = scale*(A8 @ B8^T + corrections) ----------------------
// A: [M][K] i8 row-major, B: [N][K] i8 row-major (pre-transposed y).
// Block = 256 thr / 4 waves, tile 128x128, BK=64. Wave (wr,wc) owns 64x64,
// as 2x2 MFMAs of 32x32x32_i8.
__global__ __launch_bounds__(256) void gemm_i8_kernel(
    const char* __restrict__ A, const char* __restrict__ B,
    const int* __restrict__ rsx, const int* __restrict__ csy,
    float* __restrict__ out) {
  __shared__ __align__(16) char As[128 * 64];
  __shared__ __align__(16) char Bs[128 * 64];
  const int t = threadIdx.x;
  const int l = t & 63;
  const int w = t >> 6;
  const int wr = w >> 1;
  const int wc = w & 1;
  const int bm = blockIdx.y * 128;
  const int bn = blockIdx.x * 128;

  v16i acc[2][2];
#pragma unroll
  for (int i = 0; i < 2; ++i)
#pragma unroll
    for (int j = 0; j < 2; ++j)
#pragma unroll
      for (int q = 0; q < 16; ++q) acc[i][j][q] = 0;

  // Staging: thread t handles LDS row srow (and srow+64), 16B chunk (t&3).
  // XOR-swizzle: LDS slot (t&3) receives global chunk (t&3)^(srow&3) so that
  // the MFMA fragment column-reads spread across all 32 banks.
  const int srow = t >> 2;
  const int cswz = (t & 3) ^ (srow & 3);
  const char* gA = A + (size_t)(bm + srow) * Kdim + cswz * 16;
  const char* gB = B + (size_t)(bn + srow) * Kdim + cswz * 16;
  char* lA = As + t * 16;
  char* lB = Bs + t * 16;

  const int am = wr * 64 + (l & 31);   // A row (i adds 32)
  const int bnr = wc * 64 + (l & 31);  // B row (j adds 32)
  const int lhalf = l >> 5;            // k-half selector
  const int lswz = l & 3;              // == (frag row)&3, swizzle key

  for (int kt = 0; kt < 64; ++kt) {
    const int koff = kt * 64;
    gload_lds16(gA + koff, lA);
    gload_lds16(gA + koff + (size_t)64 * Kdim, lA + 64 * 64);
    gload_lds16(gB + koff, lB);
    gload_lds16(gB + koff + (size_t)64 * Kdim, lB + 64 * 64);
    __syncthreads();  // drains vmcnt -> LDS valid
#pragma unroll
    for (int ks = 0; ks < 2; ++ks) {
      const int c0 = ((ks * 2 + lhalf) ^ lswz) * 16;  // swizzled chunk offset
      v4i a0 = *(const v4i*)(As + (am)*64 + c0);
      v4i a1 = *(const v4i*)(As + (am + 32) * 64 + c0);
      v4i b0 = *(const v4i*)(Bs + (bnr)*64 + c0);
      v4i b1 = *(const v4i*)(Bs + (bnr + 32) * 64 + c0);
      acc[0][0] = __builtin_amdgcn_mfma_i32_32x32x32_i8(a0, b0, acc[0][0], 0, 0, 0);
      acc[0][1] = __builtin_amdgcn_mfma_i32_32x32x32_i8(a0, b1, acc[0][1], 0, 0, 0);
      acc[1][0] = __builtin_amdgcn_mfma_i32_32x32x32_i8(a1, b0, acc[1][0], 0, 0, 0);
      acc[1][1] = __builtin_amdgcn_mfma_i32_32x32x32_i8(a1, b1, acc[1][1], 0, 0, 0);
    }
    __syncthreads();  // before next stage overwrites LDS
  }

  // Epilogue. C/D layout (32x32, HW-verified, dtype-independent):
  // col = lane&31, row = (reg&3) + 8*(reg>>2) + 4*(lane>>5)
  const int col = l & 31;
#pragma unroll
  for (int i = 0; i < 2; ++i) {
#pragma unroll
    for (int j = 0; j < 2; ++j) {
      const int gm0 = bm + wr * 64 + i * 32;
      const int gn = bn + wc * 64 + j * 32 + col;
      const int cs = 66 * csy[gn] - 8650752;  // -2112*4096
#pragma unroll
      for (int r = 0; r < 16; ++r) {
        const int row = (r & 3) + 8 * (r >> 2) + 4 * lhalf;
        const int gm = gm0 + row;
        const int val = acc[i][j][r] - 32 * rsx[gm] + cs;
        out[(size_t)gm * Ndim + gn] = 7.5e-4f * (float)val;
      }
    }
  }
}

extern "C" void kernel_launch(void* const* d_in, const int* in_sizes, int n_in,
                              void* d_out, int out_size, void* d_ws, size_t ws_size,
                              hipStream_t stream) {
  (void)in_sizes; (void)n_in; (void)out_size; (void)ws_size;
  const int* x = (const int*)d_in[0];
  const int* y = (const int*)d_in[1];
  float* out = (float*)d_out;
  char* ws = (char*)d_ws;
  char* x8 = ws;                                           // 16 MB
  char* yt = ws + (size_t)Mdim * Kdim;                     // 16 MB
  int* rsx = (int*)(ws + (size_t)Mdim * Kdim + (size_t)Kdim * Ndim);
  int* csy = rsx + Mdim;

  pack_x_kernel<<<Mdim, 256, 0, stream>>>(x, x8, rsx);
  pack_yt_kernel<<<dim3(Ndim / 64, Kdim / 64), 256, 0, stream>>>(y, yt);
  colsum_kernel<<<Ndim, 256, 0, stream>>>(yt, csy);
  gemm_i8_kernel<<<dim3(Ndim / 128, Mdim / 128), 256, 0, stream>>>(x8, yt, rsx, csy, out);
}

// Round 2
// 256.899 us; speedup vs baseline: 1.0529x; 1.0529x over previous
//
#include <hip/hip_runtime.h>
#include <stdint.h>

#define Mdim 4096
#define Kdim 4096
#define Ndim 4096

typedef __attribute__((ext_vector_type(4))) int v4i;
typedef __attribute__((ext_vector_type(16))) int v16i;

__device__ __forceinline__ void gload_lds16(const void* g, void* l) {
  __builtin_amdgcn_global_load_lds(
      (__attribute__((address_space(1))) void*)(uintptr_t)g,
      (__attribute__((address_space(3))) void*)(uint32_t)(uintptr_t)l,
      16, 0, 0);
}

// ---- pack x (int32 [M][K] -> int8 [M][K]) + row sums -----------------------
__global__ __launch_bounds__(256) void pack_x_kernel(const int* __restrict__ x,
                                                     char* __restrict__ x8,
                                                     int* __restrict__ rsx) {
  const int row = blockIdx.x;
  const int t = threadIdx.x;
  const int4* src = (const int4*)(x + (size_t)row * Kdim) + t * 4;
  int sum = 0;
  int p[4];
#pragma unroll
  for (int i = 0; i < 4; ++i) {
    int4 v = src[i];
    sum += v.x + v.y + v.z + v.w;
    p[i] = (v.x & 0xff) | ((v.y & 0xff) << 8) | ((v.z & 0xff) << 16) | (v.w << 24);
  }
  ((int4*)x8)[(size_t)row * 256 + t] = make_int4(p[0], p[1], p[2], p[3]);
#pragma unroll
  for (int o = 32; o > 0; o >>= 1) sum += __shfl_down(sum, o, 64);
  __shared__ int red[4];
  if ((t & 63) == 0) red[t >> 6] = sum;
  __syncthreads();
  if (t == 0) rsx[row] = red[0] + red[1] + red[2] + red[3];
}

// ---- pack + transpose y (int32 [K][N] -> int8 (y-128) [N][K]) --------------
// Word-granular transpose + fused partial column sums (atomicAdd into csy).
__global__ __launch_bounds__(256) void pack_yt_kernel(const int* __restrict__ y,
                                                      char* __restrict__ yt,
                                                      int* __restrict__ csy) {
  __shared__ int wtile[64 * 24];  // [n][qword], stride 24 (16B-aligned rows)
  __shared__ int psum[4][64];
  const int t = threadIdx.x;
  const int n0 = blockIdx.x * 64;
  const int k0 = blockIdx.y * 64;
  const int nl = t & 63;   // local n (lane-coalesced)
  const int rq = t >> 6;   // 0..3
  int s = 0;
#pragma unroll
  for (int it = 0; it < 4; ++it) {
    const int q = rq + it * 4;  // k-quad 0..15
    int v0 = y[(size_t)(k0 + q * 4 + 0) * Ndim + n0 + nl];
    int v1 = y[(size_t)(k0 + q * 4 + 1) * Ndim + n0 + nl];
    int v2 = y[(size_t)(k0 + q * 4 + 2) * Ndim + n0 + nl];
    int v3 = y[(size_t)(k0 + q * 4 + 3) * Ndim + n0 + nl];
    v0 -= 128; v1 -= 128; v2 -= 128; v3 -= 128;
    s += v0 + v1 + v2 + v3;
    wtile[nl * 24 + q] = (v0 & 0xff) | ((v1 & 0xff) << 8) | ((v2 & 0xff) << 16) | (v3 << 24);
  }
  psum[rq][nl] = s;
  __syncthreads();
  // write out: 4 threads per n-row, 16B each -> 64B contiguous per row
  const int orow = t >> 2;
  const int cw = t & 3;
  int4 wv = *(const int4*)(wtile + orow * 24 + cw * 4);
  *(int4*)(yt + (size_t)(n0 + orow) * Kdim + k0 + cw * 16) = wv;
  if (t < 64) {
    int tot = psum[0][t] + psum[1][t] + psum[2][t] + psum[3][t];
    atomicAdd(csy + n0 + t, tot);
  }
}

// ---- i8 GEMM: C = 7.5e-4*(A8 @ B8^T - 32*rsx[m] + 66*csy[n] - 2112*K) ------
// Block 256 thr / 4 waves, tile 256x256, BK=64. Wave owns 128x128 as 4x4
// MFMAs of 32x32x32_i8 (0.5 ds_reads per MFMA). Double-buffered LDS with a
// SINGLE barrier per K-step: prefetch is issued before compute, drained by
// the barrier's vmcnt(0) ~1170 cy later.
__global__ __launch_bounds__(256, 1) void gemm_i8_kernel(
    const char* __restrict__ A, const char* __restrict__ B,
    const int* __restrict__ rsx, const int* __restrict__ csy,
    float* __restrict__ out) {
  __shared__ __align__(16) char lds[2 * 32768];  // buf: [As 16K | Bs 16K]
  const int t = threadIdx.x;
  const int l = t & 63;
  const int w = t >> 6;
  const int wr = w >> 1;
  const int wc = w & 1;
  const int bm = blockIdx.y * 256;
  const int bn = blockIdx.x * 256;

  v16i acc[4][4];
#pragma unroll
  for (int i = 0; i < 4; ++i)
#pragma unroll
    for (int j = 0; j < 4; ++j)
#pragma unroll
      for (int q = 0; q < 16; ++q) acc[i][j][q] = 0;

  // Staging: thread t -> LDS rows srow + i*64, chunk slot (t&3).
  // Swizzle: slot holds global chunk (t&3)^((row>>1)&3); row>>1 key is
  // (t>>3)&3, invariant across i (i*64 rows ≡ 0 mod 4 in row>>1).
  const int srow = t >> 2;
  const int cswz = ((t & 3) ^ ((t >> 3) & 3)) * 16;
  const char* gA = A + (size_t)(bm + srow) * Kdim + cswz;
  const char* gB = B + (size_t)(bn + srow) * Kdim + cswz;

#define STAGE(buf_off, koff)                                                  \
  do {                                                                        \
    _Pragma("unroll") for (int i = 0; i < 4; ++i)                             \
        gload_lds16(gA + (koff) + (size_t)i * 64 * Kdim,                      \
                    lds + (buf_off) + i * 4096 + t * 16);                     \
    _Pragma("unroll") for (int i = 0; i < 4; ++i)                             \
        gload_lds16(gB + (koff) + (size_t)i * 64 * Kdim,                      \
                    lds + (buf_off) + 16384 + i * 4096 + t * 16);             \
  } while (0)

  const int arow = wr * 128 + (l & 31);
  const int brow = wc * 128 + (l & 31);
  const int lhalf = l >> 5;
  const int lkey = (l >> 1) & 3;

#define COMPUTE(buf_off)                                                      \
  do {                                                                        \
    const char* As = lds + (buf_off);                                         \
    const char* Bs = lds + (buf_off) + 16384;                                 \
    _Pragma("unroll") for (int ks = 0; ks < 2; ++ks) {                        \
      const int slot = ((ks * 2 + lhalf) ^ lkey) * 16;                        \
      v4i a[4], b[4];                                                         \
      _Pragma("unroll") for (int i = 0; i < 4; ++i)                           \
          a[i] = *(const v4i*)(As + (arow + i * 32) * 64 + slot);             \
      _Pragma("unroll") for (int j = 0; j < 4; ++j)                           \
          b[j] = *(const v4i*)(Bs + (brow + j * 32) * 64 + slot);             \
      _Pragma("unroll") for (int i = 0; i < 4; ++i)                           \
          _Pragma("unroll") for (int j = 0; j < 4; ++j)                       \
              acc[i][j] = __builtin_amdgcn_mfma_i32_32x32x32_i8(              \
                  a[i], b[j], acc[i][j], 0, 0, 0);                            \
    }                                                                         \
  } while (0)

  STAGE(0, 0);
  __syncthreads();
  for (int kt = 0; kt < 64; kt += 2) {
    if (kt + 1 < 64) STAGE(32768, (kt + 1) * 64);
    COMPUTE(0);
    __syncthreads();
    if (kt + 2 < 64) STAGE(0, (kt + 2) * 64);
    COMPUTE(32768);
    __syncthreads();
  }

  // Epilogue. C/D 32x32 layout: col=lane&31, row=(r&3)+8*(r>>2)+4*(lane>>5)
  const int col = l & 31;
#pragma unroll
  for (int i = 0; i < 4; ++i) {
    const int gm0 = bm + wr * 128 + i * 32;
#pragma unroll
    for (int j = 0; j < 4; ++j) {
      const int gn = bn + wc * 128 + j * 32 + col;
      const int cs = 66 * csy[gn] - 8650752;  // -66*32*4096
#pragma unroll
      for (int r = 0; r < 16; ++r) {
        const int row = (r & 3) + 8 * (r >> 2) + 4 * lhalf;
        const int gm = gm0 + row;
        const int val = acc[i][j][r] - 32 * rsx[gm] + cs;
        out[(size_t)gm * Ndim + gn] = 7.5e-4f * (float)val;
      }
    }
  }
#undef STAGE
#undef COMPUTE
}

extern "C" void kernel_launch(void* const* d_in, const int* in_sizes, int n_in,
                              void* d_out, int out_size, void* d_ws, size_t ws_size,
                              hipStream_t stream) {
  (void)in_sizes; (void)n_in; (void)out_size; (void)ws_size;
  const int* x = (const int*)d_in[0];
  const int* y = (const int*)d_in[1];
  float* out = (float*)d_out;
  char* ws = (char*)d_ws;
  char* x8 = ws;                                          // 16 MB
  char* yt = ws + (size_t)Mdim * Kdim;                    // 16 MB
  int* rsx = (int*)(ws + (size_t)Mdim * Kdim + (size_t)Kdim * Ndim);
  int* csy = rsx + Mdim;

  hipMemsetAsync(csy, 0, Ndim * sizeof(int), stream);
  pack_x_kernel<<<Mdim, 256, 0, stream>>>(x, x8, rsx);
  pack_yt_kernel<<<dim3(Ndim / 64, Kdim / 64), 256, 0, stream>>>(y, yt, csy);
  gemm_i8_kernel<<<dim3(Ndim / 256, Mdim / 256), 256, 0, stream>>>(x8, yt, rsx, csy, out);
}

// Round 3
// 244.019 us; speedup vs baseline: 1.1085x; 1.0528x over previous
//
#include <hip/hip_runtime.h>
#include <stdint.h>

#define Mdim 4096
#define Kdim 4096
#define Ndim 4096

typedef __attribute__((ext_vector_type(4))) int v4i;
typedef __attribute__((ext_vector_type(16))) int v16i;

__device__ __forceinline__ void gload_lds16(const void* g, void* l) {
  __builtin_amdgcn_global_load_lds(
      (__attribute__((address_space(1))) void*)(uintptr_t)g,
      (__attribute__((address_space(3))) void*)(uint32_t)(uintptr_t)l,
      16, 0, 0);
}

// ---- pack x (int32 [M][K] -> int8 [M][K]) + row sums -----------------------
// Fully coalesced: int4 loads at lane stride 16B, dword stores.
__global__ __launch_bounds__(256) void pack_x_kernel(const int* __restrict__ x,
                                                     char* __restrict__ x8,
                                                     int* __restrict__ rsx) {
  const int row = blockIdx.x;
  const int t = threadIdx.x;
  const int4* src = (const int4*)(x + (size_t)row * Kdim);
  int* dst = (int*)(x8 + (size_t)row * Kdim);
  int sum = 0;
#pragma unroll
  for (int i = 0; i < 4; ++i) {
    int4 v = src[t + 256 * i];
    sum += v.x + v.y + v.z + v.w;
    dst[t + 256 * i] =
        (v.x & 0xff) | ((v.y & 0xff) << 8) | ((v.z & 0xff) << 16) | (v.w << 24);
  }
#pragma unroll
  for (int o = 32; o > 0; o >>= 1) sum += __shfl_down(sum, o, 64);
  __shared__ int red[4];
  if ((t & 63) == 0) red[t >> 6] = sum;
  __syncthreads();
  if (t == 0) rsx[row] = red[0] + red[1] + red[2] + red[3];
}

// ---- pack + transpose y (int32 [K][N] -> int8 (y-128) [N][K]) + colsum -----
// 64x64 tile. Phase 1: int4 coalesced loads, word-packed into LDS [k][nq]
// stride 17 (<=3-way banks). Phase 2: byte-gather (broadcast-heavy reads),
// int4 coalesced stores, colsum fused via quad shfl_xor + 1 atomic per n.
__global__ __launch_bounds__(256) void pack_yt_kernel(const int* __restrict__ y,
                                                      char* __restrict__ yt,
                                                      int* __restrict__ csy) {
  __shared__ int wt[64 * 17];
  const int t = threadIdx.x;
  const int n0 = blockIdx.x * 64;
  const int k0 = blockIdx.y * 64;
  const int c = t & 15;   // n-quad
  const int r0 = t >> 4;  // 0..15
#pragma unroll
  for (int s = 0; s < 4; ++s) {
    const int r = r0 + s * 16;  // k row 0..63
    int4 v = *(const int4*)(y + (size_t)(k0 + r) * Ndim + n0 + c * 4);
    v.x -= 128; v.y -= 128; v.z -= 128; v.w -= 128;
    wt[r * 17 + c] =
        (v.x & 0xff) | ((v.y & 0xff) << 8) | ((v.z & 0xff) << 16) | (v.w << 24);
  }
  __syncthreads();
  const int n = t >> 2;        // 0..63
  const int kq = t & 3;        // 16-k chunk
  const int colw = n >> 2;     // LDS word column
  const int byi = (n & 3) * 8; // byte select
  int outw[4];
  int bsum = 0;
#pragma unroll
  for (int j = 0; j < 4; ++j) {
    int b[4];
#pragma unroll
    for (int jj = 0; jj < 4; ++jj) {
      const int word = wt[(kq * 16 + j * 4 + jj) * 17 + colw];
      b[jj] = (word >> byi) & 0xff;
      bsum += (int)(char)b[jj];
    }
    outw[j] = b[0] | (b[1] << 8) | (b[2] << 16) | (b[3] << 24);
  }
  *(int4*)(yt + (size_t)(n0 + n) * Kdim + k0 + kq * 16) =
      make_int4(outw[0], outw[1], outw[2], outw[3]);
  bsum += __shfl_xor(bsum, 1, 64);
  bsum += __shfl_xor(bsum, 2, 64);
  if (kq == 0) atomicAdd(csy + n0 + n, bsum);
}

// ---- i8 GEMM: C = 7.5e-4*(A8 @ B8^T - 32*rsx[m] + 66*csy[n] - 2112*K) ------
// 512 thr / 8 waves, tile 256x256, BK=64, 2 waves/SIMD for latency hiding.
// Wave owns 64x128 as 2x4 MFMAs of 32x32x32_i8 (128 AGPR acc, ~200 VGPR).
// Double-buffered LDS, single barrier per K-step; prefetch issued before
// compute so the barrier's vmcnt drain hits ~1170-cy-old loads.
__global__ __launch_bounds__(512, 2) void gemm_i8_kernel(
    const char* __restrict__ A, const char* __restrict__ B,
    const int* __restrict__ rsx, const int* __restrict__ csy,
    float* __restrict__ out) {
  __shared__ __align__(16) char lds[2 * 32768];  // buf: [As 16K | Bs 16K]
  const int t = threadIdx.x;
  const int l = t & 63;
  const int w = t >> 6;      // 0..7
  const int warow = w >> 1;  // 0..3 (x64 rows)
  const int wbcol = w & 1;   // 0..1 (x128 cols)
  const int bm = blockIdx.y * 256;
  const int bn = blockIdx.x * 256;

  v16i acc[2][4];
#pragma unroll
  for (int i = 0; i < 2; ++i)
#pragma unroll
    for (int j = 0; j < 4; ++j)
#pragma unroll
      for (int q = 0; q < 16; ++q) acc[i][j][q] = 0;

  // Staging: thread t -> LDS row srow (+128), 16B slot (t&3); slot holds
  // global chunk (t&3)^((row>>1)&3); key (t>>3)&3 invariant under +128.
  const int srow = t >> 2;  // 0..127
  const int cswz = ((t & 3) ^ ((t >> 3) & 3)) * 16;
  const char* gA = A + (size_t)(bm + srow) * Kdim + cswz;
  const char* gB = B + (size_t)(bn + srow) * Kdim + cswz;

#define STAGE(buf_off, koff)                                                  \
  do {                                                                        \
    _Pragma("unroll") for (int i = 0; i < 2; ++i)                             \
        gload_lds16(gA + (koff) + (size_t)i * 128 * Kdim,                     \
                    lds + (buf_off) + i * 8192 + t * 16);                     \
    _Pragma("unroll") for (int i = 0; i < 2; ++i)                             \
        gload_lds16(gB + (koff) + (size_t)i * 128 * Kdim,                     \
                    lds + (buf_off) + 16384 + i * 8192 + t * 16);             \
  } while (0)

  const int arow = warow * 64 + (l & 31);
  const int brow = wbcol * 128 + (l & 31);
  const int lhalf = l >> 5;
  const int lkey = (l >> 1) & 3;  // == (frag_row>>1)&3 for all frag rows

#define COMPUTE(buf_off)                                                      \
  do {                                                                        \
    const char* As = lds + (buf_off);                                         \
    const char* Bs = lds + (buf_off) + 16384;                                 \
    _Pragma("unroll") for (int ks = 0; ks < 2; ++ks) {                        \
      const int slot = ((ks * 2 + lhalf) ^ lkey) * 16;                        \
      v4i a[2], b[4];                                                         \
      _Pragma("unroll") for (int i = 0; i < 2; ++i)                           \
          a[i] = *(const v4i*)(As + (arow + i * 32) * 64 + slot);             \
      _Pragma("unroll") for (int j = 0; j < 4; ++j)                           \
          b[j] = *(const v4i*)(Bs + (brow + j * 32) * 64 + slot);             \
      _Pragma("unroll") for (int i = 0; i < 2; ++i)                           \
          _Pragma("unroll") for (int j = 0; j < 4; ++j)                       \
              acc[i][j] = __builtin_amdgcn_mfma_i32_32x32x32_i8(              \
                  a[i], b[j], acc[i][j], 0, 0, 0);                            \
    }                                                                         \
  } while (0)

  STAGE(0, 0);
  __syncthreads();
  for (int kt = 0; kt < 64; kt += 2) {
    if (kt + 1 < 64) STAGE(32768, (kt + 1) * 64);
    COMPUTE(0);
    __syncthreads();
    if (kt + 2 < 64) STAGE(0, (kt + 2) * 64);
    COMPUTE(32768);
    __syncthreads();
  }

  // Epilogue. C/D 32x32 layout: col=lane&31, row=(r&3)+8*(r>>2)+4*(lane>>5)
  const int col = l & 31;
#pragma unroll
  for (int i = 0; i < 2; ++i) {
    const int gm0 = bm + warow * 64 + i * 32;
#pragma unroll
    for (int j = 0; j < 4; ++j) {
      const int gn = bn + wbcol * 128 + j * 32 + col;
      const int cs = 66 * csy[gn] - 8650752;  // -2112*4096
#pragma unroll
      for (int r = 0; r < 16; ++r) {
        const int row = (r & 3) + 8 * (r >> 2) + 4 * lhalf;
        const int gm = gm0 + row;
        const int val = acc[i][j][r] - 32 * rsx[gm] + cs;
        out[(size_t)gm * Ndim + gn] = 7.5e-4f * (float)val;
      }
    }
  }
#undef STAGE
#undef COMPUTE
}

extern "C" void kernel_launch(void* const* d_in, const int* in_sizes, int n_in,
                              void* d_out, int out_size, void* d_ws, size_t ws_size,
                              hipStream_t stream) {
  (void)in_sizes; (void)n_in; (void)out_size; (void)ws_size;
  const int* x = (const int*)d_in[0];
  const int* y = (const int*)d_in[1];
  float* out = (float*)d_out;
  char* ws = (char*)d_ws;
  char* x8 = ws;                                          // 16 MB
  char* yt = ws + (size_t)Mdim * Kdim;                    // 16 MB
  int* rsx = (int*)(ws + (size_t)Mdim * Kdim + (size_t)Kdim * Ndim);
  int* csy = rsx + Mdim;

  hipMemsetAsync(csy, 0, Ndim * sizeof(int), stream);
  pack_x_kernel<<<Mdim, 256, 0, stream>>>(x, x8, rsx);
  pack_yt_kernel<<<dim3(Ndim / 64, Kdim / 64), 256, 0, stream>>>(y, yt, csy);
  gemm_i8_kernel<<<dim3(Ndim / 256, Mdim / 256), 512, 0, stream>>>(x8, yt, rsx, csy, out);
}